// Round 17
// baseline (69.375 us; speedup 1.0000x reference)
//
#include <hip/hip_runtime.h>
#include <hip/hip_fp16.h>

#define H1F 16
#define BSH 8                 // 256 nodes per bucket
#define BNODES 256
#define MAXBUCK 512           // supports N <= 131072
#define CAPSH 13              // 8192 edge slots per bucket window (mean ~4092)
#define CAPB (1 << CAPSH)
#define SSH 10                // 1024 slots per (bucket, xcd-shard) sub-window
#define TILE 4096             // edges per partition tile (512 thr x 8)
#define MAXPT 16              // sort register window (8 shards x 2 rounds)

struct Params {
    const float* x;
    const float* Wl1; const float* Wr1; const float* b1;
    const float* Wl2; const float* Wr2; const float* b2;
    const int* ei;
    int* cur8;
    unsigned int* edge2;
    int* csr; int* offp; int* degv;
    __half* xl; float* xr; float* hl2; float* outp;
    float* out;
    int N, E, nPart, nProj, nbuck;
};

union SharedU {
    struct {
        int lhist[MAXBUCK];
        int lbase[MAXBUCK];
        int gbase[MAXBUCK];
        int wsum[8];
        unsigned int stage[TILE];
        unsigned short sbuck[TILE];
    } p;
    struct {
        float4 wl4[16][17];   // +1 float4 pad
        float4 wr4[16][17];
    } q;
};

// ---------------------------------------------------------------------------
// part: partition one 4096-edge tile into per-(bucket, xcd-shard) sub-windows.
// Cursors XCD-local (shard = blockIdx & 7 under round-robin dispatch).
// edge2 entry = (src << 8) | (dst & 255). cur8 RELATIVE (memset 0).
// ---------------------------------------------------------------------------
__device__ __forceinline__ void do_part(const Params& P, int vb, SharedU& sh) {
    int t = threadIdx.x;
    int shard = vb & 7;
    sh.p.lhist[t] = 0;
    __syncthreads();

    int E = P.E;
    int e0 = vb * TILE;
    int eb = e0 + t * 8;

    int ss[8], dd[8];
    if (eb + 8 <= E) {
        int4 s0 = *(const int4*)(P.ei + eb);
        int4 s1 = *(const int4*)(P.ei + eb + 4);
        int4 d0 = *(const int4*)(P.ei + E + eb);
        int4 d1 = *(const int4*)(P.ei + E + eb + 4);
        ss[0]=s0.x; ss[1]=s0.y; ss[2]=s0.z; ss[3]=s0.w;
        ss[4]=s1.x; ss[5]=s1.y; ss[6]=s1.z; ss[7]=s1.w;
        dd[0]=d0.x; dd[1]=d0.y; dd[2]=d0.z; dd[3]=d0.w;
        dd[4]=d1.x; dd[5]=d1.y; dd[6]=d1.z; dd[7]=d1.w;
    } else {
#pragma unroll
        for (int k = 0; k < 8; ++k) {
            int e = eb + k;
            ss[k] = (e < E) ? P.ei[e] : -1;
            dd[k] = (e < E) ? P.ei[E + e] : 0;
        }
    }

    unsigned int pk[8];
    int rk[8], bk[8];
#pragma unroll
    for (int k = 0; k < 8; ++k) {
        if (ss[k] >= 0) {
            int b = dd[k] >> BSH;
            bk[k] = b;
            pk[k] = ((unsigned int)ss[k] << BSH) |
                    (unsigned int)(dd[k] & (BNODES - 1));
            rk[k] = atomicAdd(&sh.p.lhist[b], 1);
        } else {
            bk[k] = -1;
        }
    }
    __syncthreads();

    int cnt = E - e0; if (cnt > TILE) cnt = TILE;

    int v = sh.p.lhist[t];
    if (v > 0)
        sh.p.gbase[t] = (t << CAPSH) + (shard << SSH) +
                        atomicAdd(&P.cur8[shard * MAXBUCK + t], v);
    int lane = t & 63, wid = t >> 6;
    int s = v;
#pragma unroll
    for (int d = 1; d < 64; d <<= 1) {
        int u = __shfl_up(s, d);
        if (lane >= d) s += u;
    }
    if (lane == 63) sh.p.wsum[wid] = s;
    __syncthreads();
    int wofs = 0;
    for (int w = 0; w < wid; ++w) wofs += sh.p.wsum[w];
    sh.p.lbase[t] = wofs + s - v;
    __syncthreads();

#pragma unroll
    for (int k = 0; k < 8; ++k) {
        if (bk[k] >= 0) {
            int p = sh.p.lbase[bk[k]] + rk[k];
            sh.p.stage[p] = pk[k];
            sh.p.sbuck[p] = (unsigned short)bk[k];
        }
    }
    __syncthreads();

    for (int i = t; i < cnt; i += 512) {
        int b = sh.p.sbuck[i];
        int idx = sh.p.gbase[b] + (i - sh.p.lbase[b]);
        int shardEnd = (b << CAPSH) + ((shard + 1) << SSH);
        if (idx < shardEnd) P.edge2[idx] = sh.p.stage[i];   // stat. never hit
    }
}

// ---------------------------------------------------------------------------
// proj: xl = x @ Wl1^T (fp16), xr = x @ Wr1^T + b1 for 256 nodes/block.
// 4 nodes per thread per pass: one LDS weight-pair read feeds 32 FMAs
// (was 8), 2 passes. f = t&15, g = t>>4.
// ---------------------------------------------------------------------------
__device__ __forceinline__ void do_proj(const Params& P, int pvb, SharedU& sh) {
    int t = threadIdx.x;
    if (t < 256) {
        sh.q.wl4[t >> 4][t & 15] = ((const float4*)P.Wl1)[t];
    } else {
        int u = t - 256;
        sh.q.wr4[u >> 4][u & 15] = ((const float4*)P.Wr1)[u];
    }
    __syncthreads();

    int f = t & 15;
    int g = t >> 4;           // 0..31
    float bf = P.b1[f];
    const float4* x4 = (const float4*)P.x;

#pragma unroll
    for (int pass = 0; pass < 2; ++pass) {
        int n0 = pvb * 256 + pass * 128 + g * 4;
        if (n0 >= P.N) break;
        bool full = (n0 + 4 <= P.N);

        float al0 = 0.f, al1 = 0.f, al2 = 0.f, al3 = 0.f;
        float ar0 = 0.f, ar1 = 0.f, ar2 = 0.f, ar3 = 0.f;

        if (full) {
#pragma unroll
            for (int k4 = 0; k4 < 16; ++k4) {
                float4 wa = sh.q.wl4[f][k4];
                float4 wb = sh.q.wr4[f][k4];
                float4 v0 = x4[(size_t)(n0 + 0) * 16 + k4];
                float4 v1 = x4[(size_t)(n0 + 1) * 16 + k4];
                float4 v2 = x4[(size_t)(n0 + 2) * 16 + k4];
                float4 v3 = x4[(size_t)(n0 + 3) * 16 + k4];
                al0 += v0.x*wa.x + v0.y*wa.y + v0.z*wa.z + v0.w*wa.w;
                ar0 += v0.x*wb.x + v0.y*wb.y + v0.z*wb.z + v0.w*wb.w;
                al1 += v1.x*wa.x + v1.y*wa.y + v1.z*wa.z + v1.w*wa.w;
                ar1 += v1.x*wb.x + v1.y*wb.y + v1.z*wb.z + v1.w*wb.w;
                al2 += v2.x*wa.x + v2.y*wa.y + v2.z*wa.z + v2.w*wa.w;
                ar2 += v2.x*wb.x + v2.y*wb.y + v2.z*wb.z + v2.w*wb.w;
                al3 += v3.x*wa.x + v3.y*wa.y + v3.z*wa.z + v3.w*wa.w;
                ar3 += v3.x*wb.x + v3.y*wb.y + v3.z*wb.z + v3.w*wb.w;
            }
            P.xl[(size_t)(n0 + 0) * H1F + f] = __float2half(al0);
            P.xl[(size_t)(n0 + 1) * H1F + f] = __float2half(al1);
            P.xl[(size_t)(n0 + 2) * H1F + f] = __float2half(al2);
            P.xl[(size_t)(n0 + 3) * H1F + f] = __float2half(al3);
            P.xr[(size_t)(n0 + 0) * H1F + f] = ar0 + bf;
            P.xr[(size_t)(n0 + 1) * H1F + f] = ar1 + bf;
            P.xr[(size_t)(n0 + 2) * H1F + f] = ar2 + bf;
            P.xr[(size_t)(n0 + 3) * H1F + f] = ar3 + bf;
        } else {
            for (int i = 0; i < 4; ++i) {
                int gn = n0 + i;
                if (gn >= P.N) break;
                float al = 0.f, ar = 0.f;
#pragma unroll
                for (int k4 = 0; k4 < 16; ++k4) {
                    float4 wa = sh.q.wl4[f][k4];
                    float4 wb = sh.q.wr4[f][k4];
                    float4 v = x4[(size_t)gn * 16 + k4];
                    al += v.x*wa.x + v.y*wa.y + v.z*wa.z + v.w*wa.w;
                    ar += v.x*wb.x + v.y*wb.y + v.z*wb.z + v.w*wb.w;
                }
                P.xl[(size_t)gn * H1F + f] = __float2half(al);
                P.xr[(size_t)gn * H1F + f] = ar + bf;
            }
        }
    }
}

// ---------------------------------------------------------------------------
// kA: blocks [0,nPart) partition; blocks [nPart,...) project. Independent.
// ---------------------------------------------------------------------------
__global__ __launch_bounds__(512) void kA(Params P) {
    __shared__ SharedU sh;
    int vb = blockIdx.x;
    if (vb < P.nPart) do_part(P, vb, sh);
    else do_proj(P, vb - P.nPart, sh);
}

// ---------------------------------------------------------------------------
// kBC: per-bucket counting-sort INTO LDS, then gather1 straight from LDS
// (fused mean + self + bias + ReLU + layer-2 projections). Writes csr
// (coalesced) for kD, degv/offp, hl2, outp. Block b runs on XCD b%8 for
// both phases -> csr lands in the L2 kD will read it from.
// ---------------------------------------------------------------------------
__global__ __launch_bounds__(512) void kBC(Params P) {
    __shared__ int sorted[CAPB];   // 32KB
    __shared__ int hh[BNODES];
    __shared__ int ofs[BNODES];
    __shared__ int dgs[BNODES];
    __shared__ int wsum[4];

    int t = threadIdx.x;
    int b = blockIdx.x;
    int n0 = b << BSH;
    int e0 = b << CAPSH;

    if (t < BNODES) hh[t] = 0;
    __syncthreads();

    int cnt = 0;
    unsigned int rw[MAXPT];
#pragma unroll
    for (int s = 0; s < 8; ++s) {
        int c = P.cur8[s * MAXBUCK + b];
        if (c > (1 << SSH)) c = (1 << SSH);
        cnt += c;
        int base = e0 + (s << SSH);
#pragma unroll
        for (int k = 0; k < 2; ++k) {
            int idx = (k << 9) + t;
            rw[s * 2 + k] = (idx < c) ? P.edge2[base + idx] : 0xFFFFFFFFu;
        }
    }

#pragma unroll
    for (int k = 0; k < MAXPT; ++k)
        if (rw[k] != 0xFFFFFFFFu) atomicAdd(&hh[rw[k] & (BNODES - 1)], 1);
    __syncthreads();

    int lane = t & 63, wid = t >> 6;
    int v = 0, s = 0;
    if (t < BNODES) {
        v = hh[t];
        s = v;
#pragma unroll
        for (int d = 1; d < 64; d <<= 1) {
            int u = __shfl_up(s, d);
            if (lane >= d) s += u;
        }
        if (lane == 63) wsum[wid] = s;
    }
    __syncthreads();
    if (t < BNODES) {
        int wofs = 0;
        for (int w = 0; w < wid; ++w) wofs += wsum[w];
        int excl = wofs + s - v;
        ofs[t] = excl;
        dgs[t] = v;
        int gn = n0 + t;
        if (gn < P.N) {
            P.degv[gn] = v;
            P.offp[gn] = e0 + excl;
        }
        hh[t] = excl;         // reuse as per-node cursor
    }
    __syncthreads();

#pragma unroll
    for (int k = 0; k < MAXPT; ++k) {
        if (rw[k] != 0xFFFFFFFFu) {
            int d = (int)(rw[k] & (BNODES - 1));
            int pos = atomicAdd(&hh[d], 1);
            sorted[pos] = (int)(rw[k] >> BSH);
        }
    }
    __syncthreads();

    // coalesced csr copy for kD (bucket window, XCD-local L2)
    for (int i = t; i < cnt; i += 512) P.csr[e0 + i] = sorted[i];

    // ---- gather1 from LDS: 64 nodes x 8 lanes per pass, 4 passes ----
    const __half2* xl2 = (const __half2*)P.xl;
    const float2* xr2 = (const float2*)P.xr;
    int l = t & 7;
    int nb = t >> 3;          // 0..63
    float2 wlv = ((const float2*)P.Wl2)[l];
    float2 wrv = ((const float2*)P.Wr2)[l];
    float bias2 = P.b2[0];

#pragma unroll
    for (int sub = 0; sub < 4; ++sub) {
        int nl = sub * 64 + nb;
        int node = n0 + nl;
        if (node < P.N) {
            int start = ofs[nl];
            int d = dgs[nl];
            float sx = 0.0f, sy = 0.0f;
            int j = 0;
            for (; j + 4 <= d; j += 4) {
                int s0 = sorted[start + j], s1 = sorted[start + j + 1];
                int s2 = sorted[start + j + 2], s3 = sorted[start + j + 3];
                float2 v0 = __half22float2(xl2[(size_t)s0 * 8 + l]);
                float2 v1 = __half22float2(xl2[(size_t)s1 * 8 + l]);
                float2 v2 = __half22float2(xl2[(size_t)s2 * 8 + l]);
                float2 v3 = __half22float2(xl2[(size_t)s3 * 8 + l]);
                sx += v0.x + v1.x + v2.x + v3.x;
                sy += v0.y + v1.y + v2.y + v3.y;
            }
            for (; j < d; ++j) {
                float2 vv = __half22float2(xl2[(size_t)sorted[start + j] * 8 + l]);
                sx += vv.x; sy += vv.y;
            }

            float inv = 1.0f / fmaxf((float)d, 1.0f);
            float2 xrv = xr2[(size_t)node * 8 + l];
            float h0 = fmaxf(sx * inv + xrv.x, 0.0f);
            float h1 = fmaxf(sy * inv + xrv.y, 0.0f);
            float pl = h0 * wlv.x + h1 * wlv.y;
            float pr = h0 * wrv.x + h1 * wrv.y;
#pragma unroll
            for (int off = 4; off; off >>= 1) {
                pl += __shfl_xor(pl, off);
                pr += __shfl_xor(pr, off);
            }
            if (l == 0) {
                P.hl2[node] = pl;
                P.outp[node] = pr + bias2;
            }
        }
    }
}

// ---------------------------------------------------------------------------
// kD: gather2, 4 lanes per node, XCD-swizzled (2 blocks per bucket x 128
// nodes; bucket b -> XCD b%8 where kBC wrote its csr window).
// ---------------------------------------------------------------------------
__global__ __launch_bounds__(512) void kD(Params P) {
    int g = blockIdx.x;
    int xcd = g & 7, r = g >> 3;
    int bi = r >> 1, k = r & 1;           // 2 blocks per bucket
    int b = bi * 8 + xcd;
    if (b >= P.nbuck) return;
    int t = threadIdx.x;
    int node = (b << BSH) + (k << 7) + (t >> 2);
    int l = t & 3;
    if (node >= P.N) return;

    int d = P.degv[node];
    const int* row = P.csr + P.offp[node];

    float s = 0.0f;
    for (int j = l; j < d; j += 4) s += P.hl2[row[j]];
    s += __shfl_xor(s, 1);
    s += __shfl_xor(s, 2);
    if (l == 0) P.out[node] = s / fmaxf((float)d, 1.0f) + P.outp[node];
}

extern "C" void kernel_launch(void* const* d_in, const int* in_sizes, int n_in,
                              void* d_out, int out_size, void* d_ws, size_t ws_size,
                              hipStream_t stream) {
    Params P;
    P.x   = (const float*)d_in[0];
    P.ei  = (const int*)d_in[1];
    P.Wl1 = (const float*)d_in[2];
    P.Wr1 = (const float*)d_in[3];
    P.b1  = (const float*)d_in[4];
    P.Wl2 = (const float*)d_in[5];
    P.Wr2 = (const float*)d_in[6];
    P.b2  = (const float*)d_in[7];
    P.out = (float*)d_out;

    P.N = in_sizes[0] / 64;
    P.E = in_sizes[1] / 2;
    P.nbuck = (P.N + BNODES - 1) >> BSH;      // 391 for N=100000
    P.nPart = (P.E + TILE - 1) / TILE;        // 391
    P.nProj = (P.N + 255) / 256;              // 391

    size_t win = (size_t)P.nbuck << CAPSH;
    P.cur8  = (int*)d_ws;                                   // 8*MAXBUCK
    P.edge2 = (unsigned int*)(P.cur8 + 8 * MAXBUCK);        // win
    P.csr   = (int*)(P.edge2 + win);                        // win
    P.offp  = P.csr + win;                                  // N
    P.degv  = P.offp + P.N;                                 // N
    P.xl    = (__half*)(P.degv + P.N);                      // 16N halves
    P.xr    = (float*)(P.xl + (size_t)16 * P.N);            // 16N
    P.hl2   = P.xr + (size_t)16 * P.N;                      // N
    P.outp  = P.hl2 + P.N;                                  // N

    (void)hipMemsetAsync(P.cur8, 0, 8 * MAXBUCK * sizeof(int), stream);

    kA<<<P.nPart + P.nProj, 512, 0, stream>>>(P);
    kBC<<<P.nbuck, 512, 0, stream>>>(P);
    int gridD = 8 * ((P.nbuck + 7) / 8) * 2;
    kD<<<gridD, 512, 0, stream>>>(P);
}

// Round 18
// 65.239 us; speedup vs baseline: 1.0634x; 1.0634x over previous
//
#include <hip/hip_runtime.h>
#include <hip/hip_fp16.h>

#define H1F 16
#define BSH 8                 // 256 nodes per bucket
#define BNODES 256
#define MAXBUCK 512           // supports N <= 131072
#define CAPSH 13              // 8192 edge slots per bucket window (mean ~4092)
#define CAPB (1 << CAPSH)
#define SSH 10                // 1024 slots per (bucket, xcd-shard) sub-window
#define TILE 8192             // edges per partition tile (512 thr x 16, 2 batches)
#define MAXPT 16              // sort register window (8 shards x 2 rounds)

struct Params {
    const float* x;
    const float* Wl1; const float* Wr1; const float* b1;
    const float* Wl2; const float* Wr2; const float* b2;
    const int* ei;
    int* cur8;
    unsigned int* edge2;
    int* csr; int* offp; int* degv;
    __half* xl; float* xr; float* hl2; float* outp;
    float* out;
    int N, E, nPart, nProj, nbuck;
};

union SharedU {
    struct {
        int lhist[MAXBUCK];       // counts, then reused as place-cursor
        int lbase[MAXBUCK];
        int gbase[MAXBUCK];
        int wsum[8];
        unsigned int stage[TILE]; // 32KB
    } p;                          // 38.1KB
    struct {
        float4 wl4[16][17];   // +1 float4 pad
        float4 wr4[16][17];
    } q;
};

// ---------------------------------------------------------------------------
// part (TILE=8192): two-pass partition into per-(bucket, xcd-shard)
// sub-windows. Pass 1 histograms (edges discarded), pass 2 reloads from
// L2-hot ei and places bucket-sorted into LDS stage; then each thread
// streams its bucket's run to edge2 (XCD-local L2 lines, fire-and-forget).
// edge2 entry = (src << 8) | (dst & 255). cur8 RELATIVE (memset 0).
// ---------------------------------------------------------------------------
__device__ __forceinline__ void do_part(const Params& P, int vb, SharedU& sh) {
    int t = threadIdx.x;
    int shard = vb & 7;
    sh.p.lhist[t] = 0;
    __syncthreads();

    int E = P.E;
    int e0 = vb * TILE;

    // ---- pass 1: histogram (dst only) ----
#pragma unroll
    for (int batch = 0; batch < 2; ++batch) {
        int eb = e0 + batch * 4096 + t * 8;
        if (eb + 8 <= E) {
            int4 d0 = *(const int4*)(P.ei + E + eb);
            int4 d1 = *(const int4*)(P.ei + E + eb + 4);
            atomicAdd(&sh.p.lhist[d0.x >> BSH], 1);
            atomicAdd(&sh.p.lhist[d0.y >> BSH], 1);
            atomicAdd(&sh.p.lhist[d0.z >> BSH], 1);
            atomicAdd(&sh.p.lhist[d0.w >> BSH], 1);
            atomicAdd(&sh.p.lhist[d1.x >> BSH], 1);
            atomicAdd(&sh.p.lhist[d1.y >> BSH], 1);
            atomicAdd(&sh.p.lhist[d1.z >> BSH], 1);
            atomicAdd(&sh.p.lhist[d1.w >> BSH], 1);
        } else {
#pragma unroll
            for (int k = 0; k < 8; ++k) {
                int e = eb + k;
                if (e < E) atomicAdd(&sh.p.lhist[P.ei[E + e] >> BSH], 1);
            }
        }
    }
    __syncthreads();

    // ---- allocation (XCD-local cursor) + exclusive scan over 512 ----
    int v = sh.p.lhist[t];
    if (v > 0)
        sh.p.gbase[t] = (t << CAPSH) + (shard << SSH) +
                        atomicAdd(&P.cur8[shard * MAXBUCK + t], v);
    int lane = t & 63, wid = t >> 6;
    int s = v;
#pragma unroll
    for (int d = 1; d < 64; d <<= 1) {
        int u = __shfl_up(s, d);
        if (lane >= d) s += u;
    }
    if (lane == 63) sh.p.wsum[wid] = s;
    __syncthreads();
    int wofs = 0;
    for (int w = 0; w < wid; ++w) wofs += sh.p.wsum[w];
    int myBase = wofs + s - v;
    sh.p.lbase[t] = myBase;
    __syncthreads();
    sh.p.lhist[t] = myBase;       // reuse as place cursor
    __syncthreads();

    // ---- pass 2: reload (L2-hot) and place bucket-sorted into stage ----
#pragma unroll
    for (int batch = 0; batch < 2; ++batch) {
        int eb = e0 + batch * 4096 + t * 8;
        if (eb + 8 <= E) {
            int4 s0 = *(const int4*)(P.ei + eb);
            int4 s1 = *(const int4*)(P.ei + eb + 4);
            int4 d0 = *(const int4*)(P.ei + E + eb);
            int4 d1 = *(const int4*)(P.ei + E + eb + 4);
            int ssv[8] = {s0.x, s0.y, s0.z, s0.w, s1.x, s1.y, s1.z, s1.w};
            int ddv[8] = {d0.x, d0.y, d0.z, d0.w, d1.x, d1.y, d1.z, d1.w};
#pragma unroll
            for (int k = 0; k < 8; ++k) {
                int b = ddv[k] >> BSH;
                int pos = atomicAdd(&sh.p.lhist[b], 1);
                sh.p.stage[pos] = ((unsigned int)ssv[k] << BSH) |
                                  (unsigned int)(ddv[k] & (BNODES - 1));
            }
        } else {
#pragma unroll
            for (int k = 0; k < 8; ++k) {
                int e = eb + k;
                if (e < E) {
                    int src = P.ei[e];
                    int dst = P.ei[E + e];
                    int b = dst >> BSH;
                    int pos = atomicAdd(&sh.p.lhist[b], 1);
                    sh.p.stage[pos] = ((unsigned int)src << BSH) |
                                      (unsigned int)(dst & (BNODES - 1));
                }
            }
        }
    }
    __syncthreads();

    // ---- run-write: thread t streams bucket t's run (XCD-local lines) ----
    int lb = sh.p.lbase[t];
    int cnt = sh.p.lhist[t] - lb;         // final count for bucket t
    if (cnt > 0) {
        int gb = sh.p.gbase[t];
        int subEnd = (t << CAPSH) + ((shard + 1) << SSH);
        int jmax = subEnd - gb;           // overflow clamp (stat. never hit)
        if (cnt < jmax) jmax = cnt;
        for (int j = 0; j < jmax; ++j)
            P.edge2[gb + j] = sh.p.stage[lb + j];
    }
}

// ---------------------------------------------------------------------------
// proj: xl = x @ Wl1^T (fp16), xr = x @ Wr1^T + b1 for 128 nodes (R16 form).
// ---------------------------------------------------------------------------
__device__ __forceinline__ void do_proj(const Params& P, int pvb, SharedU& sh) {
    int t = threadIdx.x;
    if (t < 256) {
        sh.q.wl4[t >> 4][t & 15] = ((const float4*)P.Wl1)[t];
    } else {
        int u = t - 256;
        sh.q.wr4[u >> 4][u & 15] = ((const float4*)P.Wr1)[u];
    }
    __syncthreads();

    int f = t & 15;
    int nl = t >> 4;          // 0..31
    float bf = P.b1[f];
    const float4* x4 = (const float4*)P.x;

#pragma unroll
    for (int rep = 0; rep < 4; ++rep) {
        int gn = pvb * 128 + rep * 32 + nl;
        if (gn < P.N) {
            float al = 0.0f, ar = 0.0f;
#pragma unroll
            for (int k4 = 0; k4 < 16; ++k4) {
                float4 xv = x4[(size_t)gn * 16 + k4];
                float4 a = sh.q.wl4[f][k4];
                float4 b = sh.q.wr4[f][k4];
                al += xv.x * a.x + xv.y * a.y + xv.z * a.z + xv.w * a.w;
                ar += xv.x * b.x + xv.y * b.y + xv.z * b.z + xv.w * b.w;
            }
            P.xl[(size_t)gn * H1F + f] = __float2half(al);
            P.xr[(size_t)gn * H1F + f] = ar + bf;
        }
    }
}

// ---------------------------------------------------------------------------
// kA: blocks [0,nPart) partition; blocks [nPart,...) project. Independent.
// ---------------------------------------------------------------------------
__global__ __launch_bounds__(512) void kA(Params P) {
    __shared__ SharedU sh;
    int vb = blockIdx.x;
    if (vb < P.nPart) do_part(P, vb, sh);
    else do_proj(P, vb - P.nPart, sh);
}

// ---------------------------------------------------------------------------
// kBC: per-bucket counting-sort INTO LDS, then gather1 straight from LDS
// (fused mean + self + bias + ReLU + layer-2 projections). Writes csr
// (coalesced) for kD, degv/offp, hl2, outp. Block b runs on XCD b%8 for
// both phases -> csr lands in the L2 kD will read it from.
// ---------------------------------------------------------------------------
__global__ __launch_bounds__(512) void kBC(Params P) {
    __shared__ int sorted[CAPB];   // 32KB
    __shared__ int hh[BNODES];
    __shared__ int ofs[BNODES];
    __shared__ int dgs[BNODES];
    __shared__ int wsum[4];

    int t = threadIdx.x;
    int b = blockIdx.x;
    int n0 = b << BSH;
    int e0 = b << CAPSH;

    if (t < BNODES) hh[t] = 0;
    __syncthreads();

    int cnt = 0;
    unsigned int rw[MAXPT];
#pragma unroll
    for (int s = 0; s < 8; ++s) {
        int c = P.cur8[s * MAXBUCK + b];
        if (c > (1 << SSH)) c = (1 << SSH);
        cnt += c;
        int base = e0 + (s << SSH);
#pragma unroll
        for (int k = 0; k < 2; ++k) {
            int idx = (k << 9) + t;
            rw[s * 2 + k] = (idx < c) ? P.edge2[base + idx] : 0xFFFFFFFFu;
        }
    }

#pragma unroll
    for (int k = 0; k < MAXPT; ++k)
        if (rw[k] != 0xFFFFFFFFu) atomicAdd(&hh[rw[k] & (BNODES - 1)], 1);
    __syncthreads();

    int lane = t & 63, wid = t >> 6;
    int v = 0, s = 0;
    if (t < BNODES) {
        v = hh[t];
        s = v;
#pragma unroll
        for (int d = 1; d < 64; d <<= 1) {
            int u = __shfl_up(s, d);
            if (lane >= d) s += u;
        }
        if (lane == 63) wsum[wid] = s;
    }
    __syncthreads();
    if (t < BNODES) {
        int wofs = 0;
        for (int w = 0; w < wid; ++w) wofs += wsum[w];
        int excl = wofs + s - v;
        ofs[t] = excl;
        dgs[t] = v;
        int gn = n0 + t;
        if (gn < P.N) {
            P.degv[gn] = v;
            P.offp[gn] = e0 + excl;
        }
        hh[t] = excl;         // reuse as per-node cursor
    }
    __syncthreads();

#pragma unroll
    for (int k = 0; k < MAXPT; ++k) {
        if (rw[k] != 0xFFFFFFFFu) {
            int d = (int)(rw[k] & (BNODES - 1));
            int pos = atomicAdd(&hh[d], 1);
            sorted[pos] = (int)(rw[k] >> BSH);
        }
    }
    __syncthreads();

    // coalesced csr copy for kD (bucket window, XCD-local L2)
    for (int i = t; i < cnt; i += 512) P.csr[e0 + i] = sorted[i];

    // ---- gather1 from LDS: 64 nodes x 8 lanes per pass, 4 passes ----
    const __half2* xl2 = (const __half2*)P.xl;
    const float2* xr2 = (const float2*)P.xr;
    int l = t & 7;
    int nb = t >> 3;          // 0..63
    float2 wlv = ((const float2*)P.Wl2)[l];
    float2 wrv = ((const float2*)P.Wr2)[l];
    float bias2 = P.b2[0];

#pragma unroll
    for (int sub = 0; sub < 4; ++sub) {
        int nl = sub * 64 + nb;
        int node = n0 + nl;
        if (node < P.N) {
            int start = ofs[nl];
            int d = dgs[nl];
            float sx = 0.0f, sy = 0.0f;
            int j = 0;
            for (; j + 4 <= d; j += 4) {
                int s0 = sorted[start + j], s1 = sorted[start + j + 1];
                int s2 = sorted[start + j + 2], s3 = sorted[start + j + 3];
                float2 v0 = __half22float2(xl2[(size_t)s0 * 8 + l]);
                float2 v1 = __half22float2(xl2[(size_t)s1 * 8 + l]);
                float2 v2 = __half22float2(xl2[(size_t)s2 * 8 + l]);
                float2 v3 = __half22float2(xl2[(size_t)s3 * 8 + l]);
                sx += v0.x + v1.x + v2.x + v3.x;
                sy += v0.y + v1.y + v2.y + v3.y;
            }
            for (; j < d; ++j) {
                float2 vv = __half22float2(xl2[(size_t)sorted[start + j] * 8 + l]);
                sx += vv.x; sy += vv.y;
            }

            float inv = 1.0f / fmaxf((float)d, 1.0f);
            float2 xrv = xr2[(size_t)node * 8 + l];
            float h0 = fmaxf(sx * inv + xrv.x, 0.0f);
            float h1 = fmaxf(sy * inv + xrv.y, 0.0f);
            float pl = h0 * wlv.x + h1 * wlv.y;
            float pr = h0 * wrv.x + h1 * wrv.y;
#pragma unroll
            for (int off = 4; off; off >>= 1) {
                pl += __shfl_xor(pl, off);
                pr += __shfl_xor(pr, off);
            }
            if (l == 0) {
                P.hl2[node] = pl;
                P.outp[node] = pr + bias2;
            }
        }
    }
}

// ---------------------------------------------------------------------------
// kD: gather2, 4 lanes per node, XCD-swizzled (2 blocks per bucket x 128
// nodes; bucket b -> XCD b%8 where kBC wrote its csr window).
// ---------------------------------------------------------------------------
__global__ __launch_bounds__(512) void kD(Params P) {
    int g = blockIdx.x;
    int xcd = g & 7, r = g >> 3;
    int bi = r >> 1, k = r & 1;           // 2 blocks per bucket
    int b = bi * 8 + xcd;
    if (b >= P.nbuck) return;
    int t = threadIdx.x;
    int node = (b << BSH) + (k << 7) + (t >> 2);
    int l = t & 3;
    if (node >= P.N) return;

    int d = P.degv[node];
    const int* row = P.csr + P.offp[node];

    float s = 0.0f;
    for (int j = l; j < d; j += 4) s += P.hl2[row[j]];
    s += __shfl_xor(s, 1);
    s += __shfl_xor(s, 2);
    if (l == 0) P.out[node] = s / fmaxf((float)d, 1.0f) + P.outp[node];
}

extern "C" void kernel_launch(void* const* d_in, const int* in_sizes, int n_in,
                              void* d_out, int out_size, void* d_ws, size_t ws_size,
                              hipStream_t stream) {
    Params P;
    P.x   = (const float*)d_in[0];
    P.ei  = (const int*)d_in[1];
    P.Wl1 = (const float*)d_in[2];
    P.Wr1 = (const float*)d_in[3];
    P.b1  = (const float*)d_in[4];
    P.Wl2 = (const float*)d_in[5];
    P.Wr2 = (const float*)d_in[6];
    P.b2  = (const float*)d_in[7];
    P.out = (float*)d_out;

    P.N = in_sizes[0] / 64;
    P.E = in_sizes[1] / 2;
    P.nbuck = (P.N + BNODES - 1) >> BSH;      // 391 for N=100000
    P.nPart = (P.E + TILE - 1) / TILE;        // 196
    P.nProj = (P.N + 127) / 128;              // 782

    size_t win = (size_t)P.nbuck << CAPSH;
    P.cur8  = (int*)d_ws;                                   // 8*MAXBUCK
    P.edge2 = (unsigned int*)(P.cur8 + 8 * MAXBUCK);        // win
    P.csr   = (int*)(P.edge2 + win);                        // win
    P.offp  = P.csr + win;                                  // N
    P.degv  = P.offp + P.N;                                 // N
    P.xl    = (__half*)(P.degv + P.N);                      // 16N halves
    P.xr    = (float*)(P.xl + (size_t)16 * P.N);            // 16N
    P.hl2   = P.xr + (size_t)16 * P.N;                      // N
    P.outp  = P.hl2 + P.N;                                  // N

    (void)hipMemsetAsync(P.cur8, 0, 8 * MAXBUCK * sizeof(int), stream);

    kA<<<P.nPart + P.nProj, 512, 0, stream>>>(P);
    kBC<<<P.nbuck, 512, 0, stream>>>(P);
    int gridD = 8 * ((P.nbuck + 7) / 8) * 2;
    kD<<<gridD, 512, 0, stream>>>(P);
}

// Round 19
// 64.903 us; speedup vs baseline: 1.0689x; 1.0052x over previous
//
#include <hip/hip_runtime.h>
#include <hip/hip_fp16.h>

#define H1F 16
#define BSH 8                 // 256 nodes per bucket
#define BNODES 256
#define MAXBUCK 512           // supports N <= 131072
#define CAPSH 13              // 8192 edge slots per bucket window (mean ~4092)
#define CAPB (1 << CAPSH)
#define SSH 10                // 1024 slots per (bucket, xcd-shard) sub-window
#define TILE 8192             // edges per partition tile (512 thr x 16, 2 batches)
#define MAXPT 16              // sort register window (8 shards x 2 rounds)

struct Params {
    const float* x;
    const float* Wl1; const float* Wr1; const float* b1;
    const float* Wl2; const float* Wr2; const float* b2;
    const int* ei;
    int* cur8;
    unsigned int* edge2;
    int* csr; int* offp; int* degv;
    __half* xl; float* xr; float* hl2; float* outp;
    float* out;
    int N, E, nPart, nProj, nbuck;
};

union SharedU {
    struct {
        int lhist[MAXBUCK];       // counts, then reused as place-cursor
        int lbase[MAXBUCK];
        int gbase[MAXBUCK];
        int wsum[8];
        unsigned int stage[TILE]; // 32KB
    } p;                          // 38.1KB
    struct {
        float4 wl4[16][17];   // +1 float4 pad
        float4 wr4[16][17];
    } q;
};

// ---------------------------------------------------------------------------
// part (TILE=8192): two-pass partition into per-(bucket, xcd-shard)
// sub-windows. Pass 1 histograms, pass 2 reloads from L2-hot ei and places
// bucket-sorted into LDS stage; thread t then streams bucket t's run to
// edge2 as aligned int4 stores (allocations padded to 4; pad slots filled
// with 0xFFFFFFFF sentinels that kBC already skips).
// edge2 entry = (src << 8) | (dst & 255). cur8 RELATIVE (memset 0).
// ---------------------------------------------------------------------------
__device__ __forceinline__ void do_part(const Params& P, int vb, SharedU& sh) {
    int t = threadIdx.x;
    int shard = vb & 7;
    sh.p.lhist[t] = 0;
    __syncthreads();

    int E = P.E;
    int e0 = vb * TILE;

    // ---- pass 1: histogram (dst only) ----
#pragma unroll
    for (int batch = 0; batch < 2; ++batch) {
        int eb = e0 + batch * 4096 + t * 8;
        if (eb + 8 <= E) {
            int4 d0 = *(const int4*)(P.ei + E + eb);
            int4 d1 = *(const int4*)(P.ei + E + eb + 4);
            atomicAdd(&sh.p.lhist[d0.x >> BSH], 1);
            atomicAdd(&sh.p.lhist[d0.y >> BSH], 1);
            atomicAdd(&sh.p.lhist[d0.z >> BSH], 1);
            atomicAdd(&sh.p.lhist[d0.w >> BSH], 1);
            atomicAdd(&sh.p.lhist[d1.x >> BSH], 1);
            atomicAdd(&sh.p.lhist[d1.y >> BSH], 1);
            atomicAdd(&sh.p.lhist[d1.z >> BSH], 1);
            atomicAdd(&sh.p.lhist[d1.w >> BSH], 1);
        } else {
#pragma unroll
            for (int k = 0; k < 8; ++k) {
                int e = eb + k;
                if (e < E) atomicAdd(&sh.p.lhist[P.ei[E + e] >> BSH], 1);
            }
        }
    }
    __syncthreads();

    // ---- allocation (XCD-local cursor, padded to 4) + exclusive scan ----
    int v = sh.p.lhist[t];
    if (v > 0)
        sh.p.gbase[t] = (t << CAPSH) + (shard << SSH) +
                        atomicAdd(&P.cur8[shard * MAXBUCK + t], (v + 3) & ~3);
    int lane = t & 63, wid = t >> 6;
    int s = v;
#pragma unroll
    for (int d = 1; d < 64; d <<= 1) {
        int u = __shfl_up(s, d);
        if (lane >= d) s += u;
    }
    if (lane == 63) sh.p.wsum[wid] = s;
    __syncthreads();
    int wofs = 0;
    for (int w = 0; w < wid; ++w) wofs += sh.p.wsum[w];
    int myBase = wofs + s - v;
    sh.p.lbase[t] = myBase;
    sh.p.lhist[t] = myBase;       // reuse as place cursor (same-slot writes)
    __syncthreads();

    // ---- pass 2: reload (L2-hot) and place bucket-sorted into stage ----
#pragma unroll
    for (int batch = 0; batch < 2; ++batch) {
        int eb = e0 + batch * 4096 + t * 8;
        if (eb + 8 <= E) {
            int4 s0 = *(const int4*)(P.ei + eb);
            int4 s1 = *(const int4*)(P.ei + eb + 4);
            int4 d0 = *(const int4*)(P.ei + E + eb);
            int4 d1 = *(const int4*)(P.ei + E + eb + 4);
            int ssv[8] = {s0.x, s0.y, s0.z, s0.w, s1.x, s1.y, s1.z, s1.w};
            int ddv[8] = {d0.x, d0.y, d0.z, d0.w, d1.x, d1.y, d1.z, d1.w};
#pragma unroll
            for (int k = 0; k < 8; ++k) {
                int b = ddv[k] >> BSH;
                int pos = atomicAdd(&sh.p.lhist[b], 1);
                sh.p.stage[pos] = ((unsigned int)ssv[k] << BSH) |
                                  (unsigned int)(ddv[k] & (BNODES - 1));
            }
        } else {
#pragma unroll
            for (int k = 0; k < 8; ++k) {
                int e = eb + k;
                if (e < E) {
                    int src = P.ei[e];
                    int dst = P.ei[E + e];
                    int b = dst >> BSH;
                    int pos = atomicAdd(&sh.p.lhist[b], 1);
                    sh.p.stage[pos] = ((unsigned int)src << BSH) |
                                      (unsigned int)(dst & (BNODES - 1));
                }
            }
        }
    }
    __syncthreads();

    // ---- run-write: thread t streams bucket t's run as aligned int4 ----
    int lb = sh.p.lbase[t];
    int cntB = sh.p.lhist[t] - lb;        // real count for bucket t
    if (cntB > 0) {
        int gb = sh.p.gbase[t];           // 4-aligned (padded allocations)
        int subEnd = (t << CAPSH) + ((shard + 1) << SSH);
        int padded = (cntB + 3) & ~3;
        int jmax = subEnd - gb;           // overflow clamp (stat. never hit)
        if (padded > jmax) padded = jmax;
        for (int j = 0; j < padded; j += 4) {
            int4 v4;
            v4.x = (j + 0 < cntB) ? (int)sh.p.stage[lb + j + 0] : -1;
            v4.y = (j + 1 < cntB) ? (int)sh.p.stage[lb + j + 1] : -1;
            v4.z = (j + 2 < cntB) ? (int)sh.p.stage[lb + j + 2] : -1;
            v4.w = (j + 3 < cntB) ? (int)sh.p.stage[lb + j + 3] : -1;
            *(int4*)(P.edge2 + gb + j) = v4;   // sentinel pads skipped by kBC
        }
    }
}

// ---------------------------------------------------------------------------
// proj: xl = x @ Wl1^T (fp16), xr = x @ Wr1^T + b1 for 128 nodes (R16 form).
// ---------------------------------------------------------------------------
__device__ __forceinline__ void do_proj(const Params& P, int pvb, SharedU& sh) {
    int t = threadIdx.x;
    if (t < 256) {
        sh.q.wl4[t >> 4][t & 15] = ((const float4*)P.Wl1)[t];
    } else {
        int u = t - 256;
        sh.q.wr4[u >> 4][u & 15] = ((const float4*)P.Wr1)[u];
    }
    __syncthreads();

    int f = t & 15;
    int nl = t >> 4;          // 0..31
    float bf = P.b1[f];
    const float4* x4 = (const float4*)P.x;

#pragma unroll
    for (int rep = 0; rep < 4; ++rep) {
        int gn = pvb * 128 + rep * 32 + nl;
        if (gn < P.N) {
            float al = 0.0f, ar = 0.0f;
#pragma unroll
            for (int k4 = 0; k4 < 16; ++k4) {
                float4 xv = x4[(size_t)gn * 16 + k4];
                float4 a = sh.q.wl4[f][k4];
                float4 b = sh.q.wr4[f][k4];
                al += xv.x * a.x + xv.y * a.y + xv.z * a.z + xv.w * a.w;
                ar += xv.x * b.x + xv.y * b.y + xv.z * b.z + xv.w * b.w;
            }
            P.xl[(size_t)gn * H1F + f] = __float2half(al);
            P.xr[(size_t)gn * H1F + f] = ar + bf;
        }
    }
}

// ---------------------------------------------------------------------------
// kA: blocks [0,nPart) partition; blocks [nPart,...) project. Independent.
// ---------------------------------------------------------------------------
__global__ __launch_bounds__(512) void kA(Params P) {
    __shared__ SharedU sh;
    int vb = blockIdx.x;
    if (vb < P.nPart) do_part(P, vb, sh);
    else do_proj(P, vb - P.nPart, sh);
}

// ---------------------------------------------------------------------------
// kBC: per-bucket counting-sort INTO LDS, then gather1 straight from LDS
// (fused mean + self + bias + ReLU + layer-2 projections). Writes csr
// (coalesced) for kD, degv/offp, hl2, outp. Block b runs on XCD b%8 for
// both phases -> csr lands in the L2 kD will read it from. Sentinel
// (0xFFFFFFFF) entries from part's padding are skipped everywhere.
// ---------------------------------------------------------------------------
__global__ __launch_bounds__(512) void kBC(Params P) {
    __shared__ int sorted[CAPB];   // 32KB
    __shared__ int hh[BNODES];
    __shared__ int ofs[BNODES];
    __shared__ int dgs[BNODES];
    __shared__ int wsum[4];

    int t = threadIdx.x;
    int b = blockIdx.x;
    int n0 = b << BSH;
    int e0 = b << CAPSH;

    if (t < BNODES) hh[t] = 0;
    __syncthreads();

    int cnt = 0;
    unsigned int rw[MAXPT];
#pragma unroll
    for (int s = 0; s < 8; ++s) {
        int c = P.cur8[s * MAXBUCK + b];
        if (c > (1 << SSH)) c = (1 << SSH);
        cnt += c;
        int base = e0 + (s << SSH);
#pragma unroll
        for (int k = 0; k < 2; ++k) {
            int idx = (k << 9) + t;
            rw[s * 2 + k] = (idx < c) ? P.edge2[base + idx] : 0xFFFFFFFFu;
        }
    }

#pragma unroll
    for (int k = 0; k < MAXPT; ++k)
        if (rw[k] != 0xFFFFFFFFu) atomicAdd(&hh[rw[k] & (BNODES - 1)], 1);
    __syncthreads();

    int lane = t & 63, wid = t >> 6;
    int v = 0, s = 0;
    if (t < BNODES) {
        v = hh[t];
        s = v;
#pragma unroll
        for (int d = 1; d < 64; d <<= 1) {
            int u = __shfl_up(s, d);
            if (lane >= d) s += u;
        }
        if (lane == 63) wsum[wid] = s;
    }
    __syncthreads();
    if (t < BNODES) {
        int wofs = 0;
        for (int w = 0; w < wid; ++w) wofs += wsum[w];
        int excl = wofs + s - v;
        ofs[t] = excl;
        dgs[t] = v;
        int gn = n0 + t;
        if (gn < P.N) {
            P.degv[gn] = v;
            P.offp[gn] = e0 + excl;
        }
        hh[t] = excl;         // reuse as per-node cursor
    }
    __syncthreads();

#pragma unroll
    for (int k = 0; k < MAXPT; ++k) {
        if (rw[k] != 0xFFFFFFFFu) {
            int d = (int)(rw[k] & (BNODES - 1));
            int pos = atomicAdd(&hh[d], 1);
            sorted[pos] = (int)(rw[k] >> BSH);
        }
    }
    __syncthreads();

    // coalesced csr copy for kD (bucket window, XCD-local L2)
    for (int i = t; i < cnt; i += 512) P.csr[e0 + i] = sorted[i];

    // ---- gather1 from LDS: 64 nodes x 8 lanes per pass, 4 passes ----
    const __half2* xl2 = (const __half2*)P.xl;
    const float2* xr2 = (const float2*)P.xr;
    int l = t & 7;
    int nb = t >> 3;          // 0..63
    float2 wlv = ((const float2*)P.Wl2)[l];
    float2 wrv = ((const float2*)P.Wr2)[l];
    float bias2 = P.b2[0];

#pragma unroll
    for (int sub = 0; sub < 4; ++sub) {
        int nl = sub * 64 + nb;
        int node = n0 + nl;
        if (node < P.N) {
            int start = ofs[nl];
            int d = dgs[nl];
            float sx = 0.0f, sy = 0.0f;
            int j = 0;
            for (; j + 4 <= d; j += 4) {
                int s0 = sorted[start + j], s1 = sorted[start + j + 1];
                int s2 = sorted[start + j + 2], s3 = sorted[start + j + 3];
                float2 v0 = __half22float2(xl2[(size_t)s0 * 8 + l]);
                float2 v1 = __half22float2(xl2[(size_t)s1 * 8 + l]);
                float2 v2 = __half22float2(xl2[(size_t)s2 * 8 + l]);
                float2 v3 = __half22float2(xl2[(size_t)s3 * 8 + l]);
                sx += v0.x + v1.x + v2.x + v3.x;
                sy += v0.y + v1.y + v2.y + v3.y;
            }
            for (; j < d; ++j) {
                float2 vv = __half22float2(xl2[(size_t)sorted[start + j] * 8 + l]);
                sx += vv.x; sy += vv.y;
            }

            float inv = 1.0f / fmaxf((float)d, 1.0f);
            float2 xrv = xr2[(size_t)node * 8 + l];
            float h0 = fmaxf(sx * inv + xrv.x, 0.0f);
            float h1 = fmaxf(sy * inv + xrv.y, 0.0f);
            float pl = h0 * wlv.x + h1 * wlv.y;
            float pr = h0 * wrv.x + h1 * wrv.y;
#pragma unroll
            for (int off = 4; off; off >>= 1) {
                pl += __shfl_xor(pl, off);
                pr += __shfl_xor(pr, off);
            }
            if (l == 0) {
                P.hl2[node] = pl;
                P.outp[node] = pr + bias2;
            }
        }
    }
}

// ---------------------------------------------------------------------------
// kD: gather2, 4 lanes per node, XCD-swizzled (2 blocks per bucket x 128
// nodes; bucket b -> XCD b%8 where kBC wrote its csr window).
// ---------------------------------------------------------------------------
__global__ __launch_bounds__(512) void kD(Params P) {
    int g = blockIdx.x;
    int xcd = g & 7, r = g >> 3;
    int bi = r >> 1, k = r & 1;           // 2 blocks per bucket
    int b = bi * 8 + xcd;
    if (b >= P.nbuck) return;
    int t = threadIdx.x;
    int node = (b << BSH) + (k << 7) + (t >> 2);
    int l = t & 3;
    if (node >= P.N) return;

    int d = P.degv[node];
    const int* row = P.csr + P.offp[node];

    float s = 0.0f;
    for (int j = l; j < d; j += 4) s += P.hl2[row[j]];
    s += __shfl_xor(s, 1);
    s += __shfl_xor(s, 2);
    if (l == 0) P.out[node] = s / fmaxf((float)d, 1.0f) + P.outp[node];
}

extern "C" void kernel_launch(void* const* d_in, const int* in_sizes, int n_in,
                              void* d_out, int out_size, void* d_ws, size_t ws_size,
                              hipStream_t stream) {
    Params P;
    P.x   = (const float*)d_in[0];
    P.ei  = (const int*)d_in[1];
    P.Wl1 = (const float*)d_in[2];
    P.Wr1 = (const float*)d_in[3];
    P.b1  = (const float*)d_in[4];
    P.Wl2 = (const float*)d_in[5];
    P.Wr2 = (const float*)d_in[6];
    P.b2  = (const float*)d_in[7];
    P.out = (float*)d_out;

    P.N = in_sizes[0] / 64;
    P.E = in_sizes[1] / 2;
    P.nbuck = (P.N + BNODES - 1) >> BSH;      // 391 for N=100000
    P.nPart = (P.E + TILE - 1) / TILE;        // 196
    P.nProj = (P.N + 127) / 128;              // 782

    size_t win = (size_t)P.nbuck << CAPSH;
    P.cur8  = (int*)d_ws;                                   // 8*MAXBUCK
    P.edge2 = (unsigned int*)(P.cur8 + 8 * MAXBUCK);        // win
    P.csr   = (int*)(P.edge2 + win);                        // win
    P.offp  = P.csr + win;                                  // N
    P.degv  = P.offp + P.N;                                 // N
    P.xl    = (__half*)(P.degv + P.N);                      // 16N halves
    P.xr    = (float*)(P.xl + (size_t)16 * P.N);            // 16N
    P.hl2   = P.xr + (size_t)16 * P.N;                      // N
    P.outp  = P.hl2 + P.N;                                  // N

    (void)hipMemsetAsync(P.cur8, 0, 8 * MAXBUCK * sizeof(int), stream);

    kA<<<P.nPart + P.nProj, 512, 0, stream>>>(P);
    kBC<<<P.nbuck, 512, 0, stream>>>(P);
    int gridD = 8 * ((P.nbuck + 7) / 8) * 2;
    kD<<<gridD, 512, 0, stream>>>(P);
}